// Round 1
// baseline (184.811 us; speedup 1.0000x reference)
//
#include <hip/hip_runtime.h>

// WorldModel: N=8192
//   out_h[c] = action[c] * (1 - prod_r (1 - holding[r]*D[r][c]))
//   out_d[r][c] = p1 + p2 - p1*p2,  p1 = D[r][c]*(1-action[c]), p2 = D[r][c]*(1-holding[r])
//
// Kernel 1: single pass over D. Each thread owns 4 consecutive columns
// (float4). gridDim.y row-chunks write partial column products into ws.
// Kernel 2: multiply partials per column, finish out_h.
// If ws is nullptr (tiny ws_size fallback), gridDim.y==1 and kernel 1
// writes out_h directly (its product already spans all rows).

__global__ __launch_bounds__(256) void wm_main(
    const float* __restrict__ action,
    const float* __restrict__ holding,
    const float* __restrict__ dominos,
    float* __restrict__ out_d,     // [n*n]
    float* __restrict__ ws,        // [gridDim.y * n] partial products, or nullptr
    float* __restrict__ out_h,     // [n] (used only when ws == nullptr)
    int n, int rows_per_chunk)
{
    const int c4 = (blockIdx.x * blockDim.x + threadIdx.x) * 4;
    if (c4 >= n) return;

    const int r0 = blockIdx.y * rows_per_chunk;
    int r1 = r0 + rows_per_chunk;
    if (r1 > n) r1 = n;

    const float4 av = *reinterpret_cast<const float4*>(action + c4);
    const float4 ac = make_float4(1.0f - av.x, 1.0f - av.y, 1.0f - av.z, 1.0f - av.w);

    float4 prod = make_float4(1.0f, 1.0f, 1.0f, 1.0f);

    #pragma unroll 4
    for (int r = r0; r < r1; ++r) {
        const float h  = holding[r];      // wave-uniform -> scalar load
        const float hr = 1.0f - h;
        const size_t off = (size_t)r * (size_t)n + (size_t)c4;
        const float4 v = *reinterpret_cast<const float4*>(dominos + off);

        // column product: prod *= (1 - h*v)  ==  prod - prod*(h*v)
        prod.x *= fmaf(-h, v.x, 1.0f);
        prod.y *= fmaf(-h, v.y, 1.0f);
        prod.z *= fmaf(-h, v.z, 1.0f);
        prod.w *= fmaf(-h, v.w, 1.0f);

        // next_domino = p1 + p2 - p1*p2
        float4 o;
        {
            float p1 = v.x * ac.x, p2 = v.x * hr;
            o.x = fmaf(-p1, p2, p1 + p2);
        }
        {
            float p1 = v.y * ac.y, p2 = v.y * hr;
            o.y = fmaf(-p1, p2, p1 + p2);
        }
        {
            float p1 = v.z * ac.z, p2 = v.z * hr;
            o.z = fmaf(-p1, p2, p1 + p2);
        }
        {
            float p1 = v.w * ac.w, p2 = v.w * hr;
            o.w = fmaf(-p1, p2, p1 + p2);
        }
        *reinterpret_cast<float4*>(out_d + off) = o;
    }

    if (ws) {
        *reinterpret_cast<float4*>(ws + (size_t)blockIdx.y * (size_t)n + (size_t)c4) = prod;
    } else {
        // single row-chunk: prod is the full product
        float4 oh;
        oh.x = av.x * (1.0f - prod.x);
        oh.y = av.y * (1.0f - prod.y);
        oh.z = av.z * (1.0f - prod.z);
        oh.w = av.w * (1.0f - prod.w);
        *reinterpret_cast<float4*>(out_h + c4) = oh;
    }
}

__global__ __launch_bounds__(256) void wm_reduce(
    const float* __restrict__ action,
    const float* __restrict__ ws,   // [K * n]
    float* __restrict__ out_h,      // [n]
    int n, int K)
{
    const int c4 = (blockIdx.x * blockDim.x + threadIdx.x) * 4;
    if (c4 >= n) return;

    float4 prod = make_float4(1.0f, 1.0f, 1.0f, 1.0f);
    for (int k = 0; k < K; ++k) {
        const float4 p = *reinterpret_cast<const float4*>(ws + (size_t)k * (size_t)n + (size_t)c4);
        prod.x *= p.x;
        prod.y *= p.y;
        prod.z *= p.z;
        prod.w *= p.w;
    }

    const float4 av = *reinterpret_cast<const float4*>(action + c4);
    float4 oh;
    oh.x = av.x * (1.0f - prod.x);
    oh.y = av.y * (1.0f - prod.y);
    oh.z = av.z * (1.0f - prod.z);
    oh.w = av.w * (1.0f - prod.w);
    *reinterpret_cast<float4*>(out_h + c4) = oh;
}

extern "C" void kernel_launch(void* const* d_in, const int* in_sizes, int n_in,
                              void* d_out, int out_size, void* d_ws, size_t ws_size,
                              hipStream_t stream)
{
    const int n = in_sizes[0];                 // 8192
    const float* action  = (const float*)d_in[0];
    const float* holding = (const float*)d_in[1];
    const float* dominos = (const float*)d_in[2];

    float* out_h = (float*)d_out;              // [n]
    float* out_d = out_h + n;                  // [n*n]
    float* ws    = (float*)d_ws;

    // Columns: 4 per thread, 256 threads per block.
    const int cols_per_block = 256 * 4;
    const int cb = (n + cols_per_block - 1) / cols_per_block;   // 8 for n=8192

    // Row chunks: as many as ws can hold partials for (power of two, <=256).
    const size_t max_rb_ws = ws_size / ((size_t)n * sizeof(float));
    int rb = 256;
    while (rb > 1 && ((size_t)rb > max_rb_ws || rb > n)) rb >>= 1;
    if (max_rb_ws < 1) rb = 1;                  // no usable ws -> direct path

    const int rows_per_chunk = (n + rb - 1) / rb;
    const bool use_ws = (rb > 1);

    dim3 grid1(cb, rb);
    wm_main<<<grid1, 256, 0, stream>>>(action, holding, dominos,
                                       out_d,
                                       use_ws ? ws : nullptr,
                                       out_h,
                                       n, rows_per_chunk);

    if (use_ws) {
        wm_reduce<<<dim3(cb), 256, 0, stream>>>(action, ws, out_h, n, rb);
    }
}

// Round 2
// 142.596 us; speedup vs baseline: 1.2960x; 1.2960x over previous
//
#include <hip/hip_runtime.h>

// WorldModel: N=8192
//   out_h[c] = action[c] * (1 - prod_r (1 - holding[r]*D[r][c]))
//   out_d[r][c] = p1 + p2 - p1*p2,  p1 = D[r][c]*(1-action[c]), p2 = D[r][c]*(1-holding[r])
//
// R1 change: dominos (read-once, 268 MB) and out_d (write-once, 268 MB) are
// streamed with non-temporal loads/stores (nt bit) so they don't allocate in
// L2/LLC. The 536 MB working set thrashed the 256 MiB Infinity Cache; the
// harness's pure-write fill kernel hits 7 TB/s while our mixed stream sat at
// ~3.6 TB/s. NT should move the write stream toward fill-like behavior.

typedef float v4f __attribute__((ext_vector_type(4)));

__global__ __launch_bounds__(256) void wm_main(
    const float* __restrict__ action,
    const float* __restrict__ holding,
    const float* __restrict__ dominos,
    float* __restrict__ out_d,     // [n*n]
    float* __restrict__ ws,        // [gridDim.y * n] partial products, or nullptr
    float* __restrict__ out_h,     // [n] (used only when ws == nullptr)
    int n, int rows_per_chunk)
{
    const int c4 = (blockIdx.x * blockDim.x + threadIdx.x) * 4;
    if (c4 >= n) return;

    const int r0 = blockIdx.y * rows_per_chunk;
    int r1 = r0 + rows_per_chunk;
    if (r1 > n) r1 = n;

    const float4 av = *reinterpret_cast<const float4*>(action + c4);
    const float4 ac = make_float4(1.0f - av.x, 1.0f - av.y, 1.0f - av.z, 1.0f - av.w);

    v4f prod = {1.0f, 1.0f, 1.0f, 1.0f};

    #pragma unroll 8
    for (int r = r0; r < r1; ++r) {
        const float h  = holding[r];      // wave-uniform -> scalar load, cached
        const float hr = 1.0f - h;
        const size_t off = (size_t)r * (size_t)n + (size_t)c4;

        // non-temporal 16B load: read-once stream, don't allocate in LLC
        const v4f v = __builtin_nontemporal_load(
            reinterpret_cast<const v4f*>(dominos + off));

        // column product: prod *= (1 - h*v)
        prod.x *= fmaf(-h, v.x, 1.0f);
        prod.y *= fmaf(-h, v.y, 1.0f);
        prod.z *= fmaf(-h, v.z, 1.0f);
        prod.w *= fmaf(-h, v.w, 1.0f);

        // next_domino = p1 + p2 - p1*p2
        v4f o;
        {
            float p1 = v.x * ac.x, p2 = v.x * hr;
            o.x = fmaf(-p1, p2, p1 + p2);
        }
        {
            float p1 = v.y * ac.y, p2 = v.y * hr;
            o.y = fmaf(-p1, p2, p1 + p2);
        }
        {
            float p1 = v.z * ac.z, p2 = v.z * hr;
            o.z = fmaf(-p1, p2, p1 + p2);
        }
        {
            float p1 = v.w * ac.w, p2 = v.w * hr;
            o.w = fmaf(-p1, p2, p1 + p2);
        }
        // non-temporal 16B store: write-once stream
        __builtin_nontemporal_store(o, reinterpret_cast<v4f*>(out_d + off));
    }

    if (ws) {
        *reinterpret_cast<v4f*>(ws + (size_t)blockIdx.y * (size_t)n + (size_t)c4) = prod;
    } else {
        float4 oh;
        oh.x = av.x * (1.0f - prod.x);
        oh.y = av.y * (1.0f - prod.y);
        oh.z = av.z * (1.0f - prod.z);
        oh.w = av.w * (1.0f - prod.w);
        *reinterpret_cast<float4*>(out_h + c4) = oh;
    }
}

__global__ __launch_bounds__(256) void wm_reduce(
    const float* __restrict__ action,
    const float* __restrict__ ws,   // [K * n]
    float* __restrict__ out_h,      // [n]
    int n, int K)
{
    const int c4 = (blockIdx.x * blockDim.x + threadIdx.x) * 4;
    if (c4 >= n) return;

    float4 prod = make_float4(1.0f, 1.0f, 1.0f, 1.0f);
    for (int k = 0; k < K; ++k) {
        const float4 p = *reinterpret_cast<const float4*>(ws + (size_t)k * (size_t)n + (size_t)c4);
        prod.x *= p.x;
        prod.y *= p.y;
        prod.z *= p.z;
        prod.w *= p.w;
    }

    const float4 av = *reinterpret_cast<const float4*>(action + c4);
    float4 oh;
    oh.x = av.x * (1.0f - prod.x);
    oh.y = av.y * (1.0f - prod.y);
    oh.z = av.z * (1.0f - prod.z);
    oh.w = av.w * (1.0f - prod.w);
    *reinterpret_cast<float4*>(out_h + c4) = oh;
}

extern "C" void kernel_launch(void* const* d_in, const int* in_sizes, int n_in,
                              void* d_out, int out_size, void* d_ws, size_t ws_size,
                              hipStream_t stream)
{
    const int n = in_sizes[0];                 // 8192
    const float* action  = (const float*)d_in[0];
    const float* holding = (const float*)d_in[1];
    const float* dominos = (const float*)d_in[2];

    float* out_h = (float*)d_out;              // [n]
    float* out_d = out_h + n;                  // [n*n]
    float* ws    = (float*)d_ws;

    const int cols_per_block = 256 * 4;
    const int cb = (n + cols_per_block - 1) / cols_per_block;   // 8 for n=8192

    const size_t max_rb_ws = ws_size / ((size_t)n * sizeof(float));
    int rb = 256;
    while (rb > 1 && ((size_t)rb > max_rb_ws || rb > n)) rb >>= 1;
    if (max_rb_ws < 1) rb = 1;

    const int rows_per_chunk = (n + rb - 1) / rb;
    const bool use_ws = (rb > 1);

    dim3 grid1(cb, rb);
    wm_main<<<grid1, 256, 0, stream>>>(action, holding, dominos,
                                       out_d,
                                       use_ws ? ws : nullptr,
                                       out_h,
                                       n, rows_per_chunk);

    if (use_ws) {
        wm_reduce<<<dim3(cb), 256, 0, stream>>>(action, ws, out_h, n, rb);
    }
}

// Round 3
// 136.341 us; speedup vs baseline: 1.3555x; 1.0459x over previous
//
#include <hip/hip_runtime.h>

// WorldModel: N=8192
//   out_h[c] = action[c] * (1 - prod_r (1 - holding[r]*D[r][c]))
//   out_d[r][c] = p1 + p2 - p1*p2,  p1 = D[r][c]*(1-action[c]), p2 = D[r][c]*(1-holding[r])
//
// R3 change (schedule): fully-unrolled 32-row block body (template ROWS) so
// LLVM can hoist a deep batch of independent NT loads ahead of the NT stores
// (vmcnt is in-order: interleaved load/store means every load-wait also waits
// on older stores -> write backpressure starves the read stream). VGPR capped
// at 128 via __launch_bounds__(256,4). holding[] staged to LDS once per block
// to remove in-loop scalar-load stalls. NT flags kept identical to R2 so the
// delta isolates the schedule change.

typedef float v4f __attribute__((ext_vector_type(4)));

template<int ROWS>
__global__ __launch_bounds__(256, 4) void wm_main_t(
    const float* __restrict__ action,
    const float* __restrict__ holding,
    const float* __restrict__ dominos,
    float* __restrict__ out_d,     // [n*n]
    float* __restrict__ ws,        // [gridDim.y * n]
    int n)
{
    __shared__ float sh_h[ROWS];
    __shared__ float sh_hr[ROWS];

    const int tid = threadIdx.x;
    const int r0  = blockIdx.y * ROWS;
    if (tid < ROWS) {
        const float h = holding[r0 + tid];
        sh_h[tid]  = h;
        sh_hr[tid] = 1.0f - h;
    }
    __syncthreads();

    const int c4 = (blockIdx.x * blockDim.x + tid) * 4;

    const float4 av = *reinterpret_cast<const float4*>(action + c4);
    const float acx = 1.0f - av.x, acy = 1.0f - av.y,
                acz = 1.0f - av.z, acw = 1.0f - av.w;

    const float* src = dominos + (size_t)r0 * (size_t)n + (size_t)c4;
    float*       dst = out_d   + (size_t)r0 * (size_t)n + (size_t)c4;

    v4f prod = {1.0f, 1.0f, 1.0f, 1.0f};

    #pragma unroll
    for (int k = 0; k < ROWS; ++k) {
        const v4f v = __builtin_nontemporal_load(
            reinterpret_cast<const v4f*>(src + (size_t)k * (size_t)n));
        const float h  = sh_h[k];
        const float hr = sh_hr[k];

        prod.x *= fmaf(-h, v.x, 1.0f);
        prod.y *= fmaf(-h, v.y, 1.0f);
        prod.z *= fmaf(-h, v.z, 1.0f);
        prod.w *= fmaf(-h, v.w, 1.0f);

        v4f o;
        { float p1 = v.x * acx, p2 = v.x * hr; o.x = fmaf(-p1, p2, p1 + p2); }
        { float p1 = v.y * acy, p2 = v.y * hr; o.y = fmaf(-p1, p2, p1 + p2); }
        { float p1 = v.z * acz, p2 = v.z * hr; o.z = fmaf(-p1, p2, p1 + p2); }
        { float p1 = v.w * acw, p2 = v.w * hr; o.w = fmaf(-p1, p2, p1 + p2); }

        __builtin_nontemporal_store(o,
            reinterpret_cast<v4f*>(dst + (size_t)k * (size_t)n));
    }

    *reinterpret_cast<v4f*>(ws + (size_t)blockIdx.y * (size_t)n + (size_t)c4) = prod;
}

// Generic fallback (runtime row count), also used for the no-ws path.
__global__ __launch_bounds__(256) void wm_main_generic(
    const float* __restrict__ action,
    const float* __restrict__ holding,
    const float* __restrict__ dominos,
    float* __restrict__ out_d,
    float* __restrict__ ws,        // or nullptr
    float* __restrict__ out_h,     // used when ws == nullptr
    int n, int rows_per_chunk)
{
    const int c4 = (blockIdx.x * blockDim.x + threadIdx.x) * 4;
    if (c4 >= n) return;

    const int r0 = blockIdx.y * rows_per_chunk;
    int r1 = r0 + rows_per_chunk;
    if (r1 > n) r1 = n;

    const float4 av = *reinterpret_cast<const float4*>(action + c4);
    const float4 ac = make_float4(1.0f - av.x, 1.0f - av.y, 1.0f - av.z, 1.0f - av.w);

    v4f prod = {1.0f, 1.0f, 1.0f, 1.0f};

    #pragma unroll 8
    for (int r = r0; r < r1; ++r) {
        const float h  = holding[r];
        const float hr = 1.0f - h;
        const size_t off = (size_t)r * (size_t)n + (size_t)c4;
        const v4f v = __builtin_nontemporal_load(
            reinterpret_cast<const v4f*>(dominos + off));

        prod.x *= fmaf(-h, v.x, 1.0f);
        prod.y *= fmaf(-h, v.y, 1.0f);
        prod.z *= fmaf(-h, v.z, 1.0f);
        prod.w *= fmaf(-h, v.w, 1.0f);

        v4f o;
        { float p1 = v.x * ac.x, p2 = v.x * hr; o.x = fmaf(-p1, p2, p1 + p2); }
        { float p1 = v.y * ac.y, p2 = v.y * hr; o.y = fmaf(-p1, p2, p1 + p2); }
        { float p1 = v.z * ac.z, p2 = v.z * hr; o.z = fmaf(-p1, p2, p1 + p2); }
        { float p1 = v.w * ac.w, p2 = v.w * hr; o.w = fmaf(-p1, p2, p1 + p2); }
        __builtin_nontemporal_store(o, reinterpret_cast<v4f*>(out_d + off));
    }

    if (ws) {
        *reinterpret_cast<v4f*>(ws + (size_t)blockIdx.y * (size_t)n + (size_t)c4) = prod;
    } else {
        float4 oh;
        oh.x = av.x * (1.0f - prod.x);
        oh.y = av.y * (1.0f - prod.y);
        oh.z = av.z * (1.0f - prod.z);
        oh.w = av.w * (1.0f - prod.w);
        *reinterpret_cast<float4*>(out_h + c4) = oh;
    }
}

__global__ __launch_bounds__(256) void wm_reduce(
    const float* __restrict__ action,
    const float* __restrict__ ws,   // [K * n]
    float* __restrict__ out_h,      // [n]
    int n, int K)
{
    const int c4 = (blockIdx.x * blockDim.x + threadIdx.x) * 4;
    if (c4 >= n) return;

    float4 prod = make_float4(1.0f, 1.0f, 1.0f, 1.0f);
    for (int k = 0; k < K; ++k) {
        const float4 p = *reinterpret_cast<const float4*>(ws + (size_t)k * (size_t)n + (size_t)c4);
        prod.x *= p.x;
        prod.y *= p.y;
        prod.z *= p.z;
        prod.w *= p.w;
    }

    const float4 av = *reinterpret_cast<const float4*>(action + c4);
    float4 oh;
    oh.x = av.x * (1.0f - prod.x);
    oh.y = av.y * (1.0f - prod.y);
    oh.z = av.z * (1.0f - prod.z);
    oh.w = av.w * (1.0f - prod.w);
    *reinterpret_cast<float4*>(out_h + c4) = oh;
}

extern "C" void kernel_launch(void* const* d_in, const int* in_sizes, int n_in,
                              void* d_out, int out_size, void* d_ws, size_t ws_size,
                              hipStream_t stream)
{
    const int n = in_sizes[0];                 // 8192
    const float* action  = (const float*)d_in[0];
    const float* holding = (const float*)d_in[1];
    const float* dominos = (const float*)d_in[2];

    float* out_h = (float*)d_out;              // [n]
    float* out_d = out_h + n;                  // [n*n]
    float* ws    = (float*)d_ws;

    const int cols_per_block = 256 * 4;
    const int cb = (n + cols_per_block - 1) / cols_per_block;   // 8 for n=8192

    const size_t max_rb_ws = ws_size / ((size_t)n * sizeof(float));
    int rb = 256;
    while (rb > 1 && ((size_t)rb > max_rb_ws || rb > n)) rb >>= 1;
    if (max_rb_ws < 1) rb = 1;

    const int rows_per_chunk = (n + rb - 1) / rb;
    const bool use_ws = (rb > 1);

    // Fast path: exact-fit geometry (n divisible by 1024, 32 rows/chunk).
    if (use_ws && rows_per_chunk == 32 && (n % cols_per_block) == 0 && (n % 32) == 0) {
        dim3 grid1(cb, rb);
        wm_main_t<32><<<grid1, 256, 0, stream>>>(action, holding, dominos,
                                                 out_d, ws, n);
    } else {
        dim3 grid1(cb, rb);
        wm_main_generic<<<grid1, 256, 0, stream>>>(action, holding, dominos,
                                                   out_d,
                                                   use_ws ? ws : nullptr,
                                                   out_h,
                                                   n, rows_per_chunk);
    }

    if (use_ws) {
        wm_reduce<<<dim3(cb), 256, 0, stream>>>(action, ws, out_h, n, rb);
    }
}

// Round 4
// 117.540 us; speedup vs baseline: 1.5723x; 1.1600x over previous
//
#include <hip/hip_runtime.h>

// WorldModel: N=8192
//   out_h[c] = action[c] * (1 - prod_r (1 - holding[r]*D[r][c]))
//   out_d[r][c] = p1 + p2 - p1*p2,  p1 = D[r][c]*(1-action[c]), p2 = D[r][c]*(1-holding[r])
//
// R4 change (geometry): each block owns 32 FULL rows -> a linear 1 MiB range
// for both the dominos read stream and the out_d NT-write stream (like the
// 7 TB/s fill / 6.3 TB/s copy kernels), instead of a 4KB-wide column slab at
// 32KB stride. 256 blocks x 1024 threads, 2 column-quads per thread.
// Reduce kernel re-parallelized: 32 blocks x 256 threads, 1 column/thread.

typedef float v4f __attribute__((ext_vector_type(4)));

template<int ROWS, int THREADS, int CHUNKS>
__global__ __launch_bounds__(THREADS, 4) void wm_linear(
    const float* __restrict__ action,
    const float* __restrict__ holding,
    const float* __restrict__ dominos,
    float* __restrict__ out_d,     // [n*n]
    float* __restrict__ ws,        // [n/ROWS][n] partial column products
    int n)
{
    __shared__ float sh_h[ROWS];
    __shared__ float sh_hr[ROWS];

    const int tid = threadIdx.x;
    const int b   = blockIdx.x;
    const int r0  = b * ROWS;
    if (tid < ROWS) {
        const float h = holding[r0 + tid];
        sh_h[tid]  = h;
        sh_hr[tid] = 1.0f - h;
    }
    __syncthreads();

    const v4f ones = {1.0f, 1.0f, 1.0f, 1.0f};

    v4f av[CHUNKS], ac[CHUNKS], prod[CHUNKS];
    #pragma unroll
    for (int k = 0; k < CHUNKS; ++k) {
        const int c = k * THREADS * 4 + tid * 4;
        av[k]   = *reinterpret_cast<const v4f*>(action + c);
        ac[k]   = ones - av[k];
        prod[k] = ones;
    }

    const float* src = dominos + (size_t)r0 * (size_t)n;
    float*       dst = out_d   + (size_t)r0 * (size_t)n;

    #pragma unroll 2
    for (int r = 0; r < ROWS; ++r) {
        const float h  = sh_h[r];
        const float hr = sh_hr[r];

        v4f v[CHUNKS];
        #pragma unroll
        for (int k = 0; k < CHUNKS; ++k) {
            v[k] = __builtin_nontemporal_load(reinterpret_cast<const v4f*>(
                src + (size_t)r * (size_t)n + k * THREADS * 4 + tid * 4));
        }
        #pragma unroll
        for (int k = 0; k < CHUNKS; ++k) {
            prod[k] *= (ones - v[k] * h);            // prod *= (1 - h*D)
            const v4f p1 = v[k] * ac[k];
            const v4f p2 = v[k] * hr;
            const v4f o  = p1 + p2 - p1 * p2;        // noisy-OR
            __builtin_nontemporal_store(o, reinterpret_cast<v4f*>(
                dst + (size_t)r * (size_t)n + k * THREADS * 4 + tid * 4));
        }
    }

    // ws is small (8 MB) and re-read immediately -> regular (cached) stores
    #pragma unroll
    for (int k = 0; k < CHUNKS; ++k) {
        *reinterpret_cast<v4f*>(ws + (size_t)b * (size_t)n + k * THREADS * 4 + tid * 4) = prod[k];
    }
}

__global__ __launch_bounds__(256) void wm_reduce_col(
    const float* __restrict__ action,
    const float* __restrict__ ws,   // [K][n]
    float* __restrict__ out_h,      // [n]
    int n, int K)
{
    const int c = blockIdx.x * blockDim.x + threadIdx.x;
    if (c >= n) return;

    float prod = 1.0f;
    #pragma unroll 4
    for (int k = 0; k < K; ++k) {
        prod *= ws[(size_t)k * (size_t)n + c];
    }
    out_h[c] = action[c] * (1.0f - prod);
}

// ---------- generic fallbacks (non-8192 geometry) ----------

__global__ __launch_bounds__(256) void wm_main_generic(
    const float* __restrict__ action,
    const float* __restrict__ holding,
    const float* __restrict__ dominos,
    float* __restrict__ out_d,
    float* __restrict__ ws,        // or nullptr
    float* __restrict__ out_h,     // used when ws == nullptr
    int n, int rows_per_chunk)
{
    const int c4 = (blockIdx.x * blockDim.x + threadIdx.x) * 4;
    if (c4 >= n) return;

    const int r0 = blockIdx.y * rows_per_chunk;
    int r1 = r0 + rows_per_chunk;
    if (r1 > n) r1 = n;

    const float4 av = *reinterpret_cast<const float4*>(action + c4);
    const float4 ac = make_float4(1.0f - av.x, 1.0f - av.y, 1.0f - av.z, 1.0f - av.w);

    v4f prod = {1.0f, 1.0f, 1.0f, 1.0f};

    #pragma unroll 8
    for (int r = r0; r < r1; ++r) {
        const float h  = holding[r];
        const float hr = 1.0f - h;
        const size_t off = (size_t)r * (size_t)n + (size_t)c4;
        const v4f v = __builtin_nontemporal_load(
            reinterpret_cast<const v4f*>(dominos + off));

        prod.x *= fmaf(-h, v.x, 1.0f);
        prod.y *= fmaf(-h, v.y, 1.0f);
        prod.z *= fmaf(-h, v.z, 1.0f);
        prod.w *= fmaf(-h, v.w, 1.0f);

        v4f o;
        { float p1 = v.x * ac.x, p2 = v.x * hr; o.x = fmaf(-p1, p2, p1 + p2); }
        { float p1 = v.y * ac.y, p2 = v.y * hr; o.y = fmaf(-p1, p2, p1 + p2); }
        { float p1 = v.z * ac.z, p2 = v.z * hr; o.z = fmaf(-p1, p2, p1 + p2); }
        { float p1 = v.w * ac.w, p2 = v.w * hr; o.w = fmaf(-p1, p2, p1 + p2); }
        __builtin_nontemporal_store(o, reinterpret_cast<v4f*>(out_d + off));
    }

    if (ws) {
        *reinterpret_cast<v4f*>(ws + (size_t)blockIdx.y * (size_t)n + (size_t)c4) = prod;
    } else {
        float4 oh;
        oh.x = av.x * (1.0f - prod.x);
        oh.y = av.y * (1.0f - prod.y);
        oh.z = av.z * (1.0f - prod.z);
        oh.w = av.w * (1.0f - prod.w);
        *reinterpret_cast<float4*>(out_h + c4) = oh;
    }
}

extern "C" void kernel_launch(void* const* d_in, const int* in_sizes, int n_in,
                              void* d_out, int out_size, void* d_ws, size_t ws_size,
                              hipStream_t stream)
{
    const int n = in_sizes[0];                 // 8192
    const float* action  = (const float*)d_in[0];
    const float* holding = (const float*)d_in[1];
    const float* dominos = (const float*)d_in[2];

    float* out_h = (float*)d_out;              // [n]
    float* out_d = out_h + n;                  // [n*n]
    float* ws    = (float*)d_ws;

    constexpr int ROWS    = 32;
    constexpr int THREADS = 1024;

    const bool fast =
        (n % (THREADS * 4) == 0) &&            // CHUNKS integral
        (n % ROWS == 0) &&
        ((size_t)(n / ROWS) * (size_t)n * sizeof(float) <= ws_size) &&
        (n / (THREADS * 4) == 2);              // CHUNKS == 2 instantiation

    if (fast) {
        const int nblocks = n / ROWS;          // 256
        wm_linear<ROWS, THREADS, 2><<<nblocks, THREADS, 0, stream>>>(
            action, holding, dominos, out_d, ws, n);
        wm_reduce_col<<<(n + 255) / 256, 256, 0, stream>>>(
            action, ws, out_h, n, nblocks);
    } else {
        const int cols_per_block = 256 * 4;
        const int cb = (n + cols_per_block - 1) / cols_per_block;

        const size_t max_rb_ws = ws_size / ((size_t)n * sizeof(float));
        int rb = 256;
        while (rb > 1 && ((size_t)rb > max_rb_ws || rb > n)) rb >>= 1;
        if (max_rb_ws < 1) rb = 1;

        const int rows_per_chunk = (n + rb - 1) / rb;
        const bool use_ws = (rb > 1);

        dim3 grid1(cb, rb);
        wm_main_generic<<<grid1, 256, 0, stream>>>(action, holding, dominos,
                                                   out_d,
                                                   use_ws ? ws : nullptr,
                                                   out_h,
                                                   n, rows_per_chunk);
        if (use_ws) {
            wm_reduce_col<<<(n + 255) / 256, 256, 0, stream>>>(
                action, ws, out_h, n, rb);
        }
    }
}